// Round 7
// baseline (105.176 us; speedup 1.0000x reference)
//
#include <hip/hip_runtime.h>
#include <math.h>

// PCEN, single fused kernel, v3 (explicit double-stream):
//   pass 1: stream x -> u-space partials (own 32-step chunk, 2x16 chains)
//           + balanced 16-step halo sub-partials (256-step truncation window)
//   LDS: combine halo subs, then 8-term Horner carry (weight a^32)
//   pass 2: re-stream x (L2/L3-hot), EMA + pcen, nontemporal stores
//   raw v_log_f32 / v_exp_f32 / v_sqrt_f32 via __builtin_amdgcn_* (domain-safe)
//
// M[t] = a*M[t-1] + s*x[t], M[0]=x[0]
// out  = sqrt(x*(M+eps)^-0.98 + 2) - sqrt(2)

#define B_     64
#define T_     8192
#define F4_    20                 // 80 f32 = 20 float4
#define NSEQ4  (B_ * F4_)         // 1280 float4 lanes
#define LCH_   32                 // timesteps per thread
#define SPB_   16                 // seq4 per block (lane-low bits -> 256B segments)
#define CPB_   16                 // chunks per block (256 threads)
#define SPAN_  (LCH_ * CPB_)      // 512 steps per block
#define TB_    (T_ / SPAN_)       // 16 time-blocks
#define NG_    (NSEQ4 / SPB_)     // 80 seq groups -> 1280 blocks = 5/CU, co-resident
#define HC_    8                  // halo chunks (32 steps) = 256-step window
#define SA_    0.025f
#define AA_    0.975f
#define A8_    0.81665182f        // 0.975^8
#define A16_   0.66692016f        // 0.975^16
#define A32_   0.44478250f        // 0.975^32
#define A32S_  17.791300f         // A32_/SA_ (chunk-0 exact fix, u-space)

typedef float f4v __attribute__((ext_vector_type(4)));

__device__ __forceinline__ float pcen1(float xv, float m) {
    float l = __builtin_amdgcn_logf(m + 1e-6f);        // v_log_f32 = log2
    float g = __builtin_amdgcn_exp2f(-0.98f * l);      // (m+eps)^(-alpha)
    return __builtin_amdgcn_sqrtf(fmaf(xv, g, 2.0f)) - 1.4142135623730951f;
}

__device__ __forceinline__ f4v pcen4(float4 xv, float4 m) {
    f4v o;
    o.x = pcen1(xv.x, m.x);
    o.y = pcen1(xv.y, m.y);
    o.z = pcen1(xv.z, m.z);
    o.w = pcen1(xv.w, m.w);
    return o;
}

// d = c*d + v   (u-space EMA / Horner step)
__device__ __forceinline__ void hstep(float4& d, float c, const float4 v) {
    d.x = fmaf(c, d.x, v.x);
    d.y = fmaf(c, d.y, v.y);
    d.z = fmaf(c, d.z, v.z);
    d.w = fmaf(c, d.w, v.w);
}

// d += c*v
__device__ __forceinline__ void faxpy(float4& d, float c, const float4 v) {
    d.x = fmaf(c, v.x, d.x);
    d.y = fmaf(c, v.y, d.y);
    d.z = fmaf(c, v.z, d.z);
    d.w = fmaf(c, v.w, d.w);
}

// m = a*m + s*x   (m-space EMA, produce phase)
__device__ __forceinline__ void ema4(float4& m, const float4 xv) {
    m.x = fmaf(AA_, m.x, SA_ * xv.x);
    m.y = fmaf(AA_, m.y, SA_ * xv.y);
    m.z = fmaf(AA_, m.z, SA_ * xv.z);
    m.w = fmaf(AA_, m.w, SA_ * xv.w);
}

__global__ void __launch_bounds__(256, 4)
pcen_fused(const float4* __restrict__ x4, float4* __restrict__ o4) {
    __shared__ float4 P[HC_ + CPB_][SPB_];   // rows 0..7 halo chunks, 8..23 own
    __shared__ float4 HS[CPB_][SPB_];        // 16-step halo sub-partials

    const int tid = threadIdx.x;
    const int s   = tid & (SPB_ - 1);        // seq4 within block
    const int lc  = tid >> 4;                // local chunk 0..15

    const int g   = blockIdx.x % NG_;
    const int tb  = blockIdx.x / NG_;

    const int r   = g * SPB_ + s;            // global float4-lane id
    const int b   = r / F4_;
    const int f4  = r - b * F4_;

    const size_t  seqbase = (size_t)b * ((size_t)T_ * F4_) + f4;
    const int     t0      = tb * SPAN_ + lc * LCH_;
    const float4* xp      = x4 + seqbase + (size_t)t0 * F4_;
    float4*       op      = o4 + seqbase + (size_t)t0 * F4_;

    // ---- halo sub-partial: 16 steps (u-space, two 8-chains) ----
    float4 hu = make_float4(0.f, 0.f, 0.f, 0.f);
    if (tb > 0) {                            // block-uniform branch
        const float4* hp = x4 + seqbase
                         + (size_t)(tb * SPAN_ - HC_ * 32 + lc * 16) * F4_;
        float4 u0 = make_float4(0.f, 0.f, 0.f, 0.f);
        float4 u1 = make_float4(0.f, 0.f, 0.f, 0.f);
        #pragma unroll
        for (int j = 0; j < 8; ++j) {
            hstep(u0, AA_, hp[(size_t)j * F4_]);
            hstep(u1, AA_, hp[(size_t)(j + 8) * F4_]);
        }
        hu = u1;
        faxpy(hu, A8_, u0);                  // hu = a^8*u0 + u1
    }
    HS[lc][s] = hu;

    // ---- own 32-step zero-init partial (u-space, two 16-chains) ----
    {
        float4 u0 = make_float4(0.f, 0.f, 0.f, 0.f);
        float4 u1 = make_float4(0.f, 0.f, 0.f, 0.f);
        float4 x0v = make_float4(0.f, 0.f, 0.f, 0.f);
        #pragma unroll
        for (int j = 0; j < 16; ++j) {
            float4 xa = xp[(size_t)j * F4_];
            if (j == 0) x0v = xa;            // compile-time branch (unrolled)
            hstep(u0, AA_, xa);
            hstep(u1, AA_, xp[(size_t)(j + 16) * F4_]);
        }
        float4 pu = u1;
        faxpy(pu, A16_, u0);                 // pu = a^16*u0 + u1
        const float c0 = (tb == 0 && lc == 0) ? A32S_ : 0.0f;
        faxpy(pu, c0, x0v);                  // exact M[0]=x[0] fix (u-space)
        P[HC_ + lc][s] = pu;
    }

    __syncthreads();

    // ---- combine halo subs into P rows 0..7 ----
    if (tid < HC_ * SPB_) {                  // 128 threads
        const int sc = tid & (SPB_ - 1);
        const int h  = tid >> 4;
        float4 e = HS[2 * h][sc];
        hstep(e, A16_, HS[2 * h + 1][sc]);   // e = a^16*sub0 + sub1
        P[h][sc] = e;
    }

    __syncthreads();

    // ---- carry: 8-term Horner over rows lc .. lc+7 (oldest -> newest) ----
    float4 u = P[lc][s];
    #pragma unroll
    for (int k = 1; k < HC_; ++k) hstep(u, A32_, P[lc + k][s]);

    float4 m;                                // m = s*u
    m.x = SA_ * u.x; m.y = SA_ * u.y; m.z = SA_ * u.z; m.w = SA_ * u.w;

    // ---- produce: re-stream x (cache-hot), EMA + pcen, NT stores ----
    const float fix = (tb == 0 && lc == 0) ? AA_ : 0.0f;
    {
        float4 xa = xp[0];
        ema4(m, xa);
        faxpy(m, fix, xa);                   // global t=0: m = x[0] exactly
        __builtin_nontemporal_store(pcen4(xa, m), (f4v*)op);
    }
    #pragma unroll 8
    for (int j = 1; j < LCH_; ++j) {
        float4 xa = xp[(size_t)j * F4_];
        ema4(m, xa);
        __builtin_nontemporal_store(pcen4(xa, m), (f4v*)(op + (size_t)j * F4_));
    }
}

extern "C" void kernel_launch(void* const* d_in, const int* in_sizes, int n_in,
                              void* d_out, int out_size, void* d_ws, size_t ws_size,
                              hipStream_t stream) {
    const float4* x4 = (const float4*)d_in[0];
    float4*       o4 = (float4*)d_out;

    pcen_fused<<<dim3(NG_ * TB_), dim3(256), 0, stream>>>(x4, o4);
}

// Round 8
// 90.192 us; speedup vs baseline: 1.1661x; 1.1661x over previous
//
#include <hip/hip_runtime.h>
#include <math.h>

// PCEN, single fused kernel, v4 = round-6 geometry + raw transcendentals.
//   - thread owns a 16-step chunk of one float4 lane (xv[16])
//   - block = 16 seq4 x 16 chunks = 256-step span; grid tb-major, 2560 blocks
//     (~3 resident/CU -> ~10 time-rows in flight -> 5.25MB stripes stay L3-hot)
//   - halo = previous block's span (256 steps) recomputed per thread
//   - carry = 16-term Horner over [halo | own] u-space partials in LDS,
//     weight a^16; truncation a^256 ~ 1.5e-3 (validated absmax floor 0.0039)
//   - raw v_log_f32/v_exp_f32/v_sqrt_f32 (domain-safe: m+eps in [1e-6,~1],
//     arg of sqrt in [2,~40]) -- round-7-validated, cut VALUBusy 35%->10%
//   - nontemporal output stores (don't evict x from L3)
//
// M[t] = a*M[t-1] + s*x[t], M[0]=x[0]
// out  = sqrt(x*(M+eps)^-0.98 + 2) - sqrt(2)

#define B_     64
#define T_     8192
#define F4_    20                 // 80 f32 = 20 float4
#define NSEQ4  (B_ * F4_)         // 1280 float4 lanes
#define LCH_   16                 // timesteps per thread
#define SPB_   16                 // seq4 per block (lane-low bits -> 256B segments)
#define CPB_   16                 // chunks per block (256 threads)
#define SPAN_  (LCH_ * CPB_)      // 256 steps per block
#define TB_    (T_ / SPAN_)       // 32 time-blocks
#define NG_    (NSEQ4 / SPB_)     // 80 seq groups -> grid 2560
#define SA_    0.025f
#define AA_    0.975f
#define A8_    0.81665182f        // 0.975^8
#define A16_   0.66692016f        // 0.975^16
#define A16S_  26.676807f         // A16_/SA_ (chunk-0 exact fix, u-space)

typedef float f4v __attribute__((ext_vector_type(4)));

__device__ __forceinline__ float pcen1(float xv, float m) {
    float l = __builtin_amdgcn_logf(m + 1e-6f);        // v_log_f32 (log2)
    float g = __builtin_amdgcn_exp2f(-0.98f * l);      // (m+eps)^(-alpha)
    return __builtin_amdgcn_sqrtf(fmaf(xv, g, 2.0f)) - 1.4142135623730951f;
}

__device__ __forceinline__ f4v pcen4(float4 xv, float4 m) {
    f4v o;
    o.x = pcen1(xv.x, m.x);
    o.y = pcen1(xv.y, m.y);
    o.z = pcen1(xv.z, m.z);
    o.w = pcen1(xv.w, m.w);
    return o;
}

// d = c*d + v   (u-space EMA step / Horner step)
__device__ __forceinline__ void hstep(float4& d, float c, const float4 v) {
    d.x = fmaf(c, d.x, v.x);
    d.y = fmaf(c, d.y, v.y);
    d.z = fmaf(c, d.z, v.z);
    d.w = fmaf(c, d.w, v.w);
}

// d += c*v
__device__ __forceinline__ void faxpy(float4& d, float c, const float4 v) {
    d.x = fmaf(c, v.x, d.x);
    d.y = fmaf(c, v.y, d.y);
    d.z = fmaf(c, v.z, d.z);
    d.w = fmaf(c, v.w, d.w);
}

// m = a*m + s*x   (m-space EMA, produce phase)
__device__ __forceinline__ void ema4(float4& m, const float4 xv) {
    m.x = fmaf(AA_, m.x, SA_ * xv.x);
    m.y = fmaf(AA_, m.y, SA_ * xv.y);
    m.z = fmaf(AA_, m.z, SA_ * xv.z);
    m.w = fmaf(AA_, m.w, SA_ * xv.w);
}

__global__ void __launch_bounds__(256, 4)
pcen_fused(const float4* __restrict__ x4, float4* __restrict__ o4) {
    __shared__ float4 P[2 * CPB_][SPB_];   // rows 0..15 halo, 16..31 own (u-space)

    const int tid = threadIdx.x;
    const int s   = tid & (SPB_ - 1);      // seq4 within block (lane-low bits)
    const int lc  = tid >> 4;              // local chunk 0..15

    const int g   = blockIdx.x % NG_;      // tb-major: time stripes run together
    const int tb  = blockIdx.x / NG_;

    const int r   = g * SPB_ + s;          // global float4-lane id
    const int b   = r / F4_;
    const int f4  = r - b * F4_;

    const size_t  seqbase = (size_t)b * ((size_t)T_ * F4_) + f4;
    const int     t0      = tb * SPAN_ + lc * LCH_;
    const float4* xp      = x4 + seqbase + (size_t)t0 * F4_;
    float4*       op      = o4 + seqbase + (size_t)t0 * F4_;

    // ---- own chunk -> registers (16 x float4) ----
    float4 xv[LCH_];
    #pragma unroll
    for (int j = 0; j < LCH_; ++j) xv[j] = xp[(size_t)j * F4_];

    // ---- halo partial: own chunk shifted back one span, u-space ----
    float4 hu = make_float4(0.f, 0.f, 0.f, 0.f);
    if (tb > 0) {                          // block-uniform branch
        const float4* hp = xp - (size_t)SPAN_ * F4_;
        float4 u0 = make_float4(0.f, 0.f, 0.f, 0.f);
        float4 u1 = make_float4(0.f, 0.f, 0.f, 0.f);
        #pragma unroll
        for (int j = 0; j < 8; ++j) {      // two independent 8-chains
            hstep(u0, AA_, hp[(size_t)j * F4_]);
            hstep(u1, AA_, hp[(size_t)(j + 8) * F4_]);
        }
        hu = u1;
        faxpy(hu, A8_, u0);                // hu = a^8*u0 + u1
    }
    P[lc][s] = hu;

    // ---- own zero-init partial (u-space, two 8-chains) ----
    {
        float4 u0 = make_float4(0.f, 0.f, 0.f, 0.f);
        float4 u1 = make_float4(0.f, 0.f, 0.f, 0.f);
        #pragma unroll
        for (int j = 0; j < 8; ++j) {
            hstep(u0, AA_, xv[j]);
            hstep(u1, AA_, xv[j + 8]);
        }
        float4 pu = u1;
        faxpy(pu, A8_, u0);
        const float c0 = (tb == 0 && lc == 0) ? A16S_ : 0.0f;
        faxpy(pu, c0, xv[0]);              // exact M[0]=x[0] fix (u-space)
        P[CPB_ + lc][s] = pu;
    }

    __syncthreads();

    // ---- carry: 16-term Horner over rows lc .. lc+15 (oldest -> newest) ----
    float4 u = P[lc][s];
    #pragma unroll
    for (int k = 1; k < CPB_; ++k) hstep(u, A16_, P[lc + k][s]);

    float4 m;                              // m = s*u
    m.x = SA_ * u.x; m.y = SA_ * u.y; m.z = SA_ * u.z; m.w = SA_ * u.w;

    // ---- produce: EMA + pcen from register x, nontemporal stores ----
    const float fix = (tb == 0 && lc == 0) ? AA_ : 0.0f;
    ema4(m, xv[0]);
    faxpy(m, fix, xv[0]);                  // global t=0: m = x[0] exactly
    __builtin_nontemporal_store(pcen4(xv[0], m), (f4v*)op);
    #pragma unroll
    for (int j = 1; j < LCH_; ++j) {
        ema4(m, xv[j]);
        __builtin_nontemporal_store(pcen4(xv[j], m), (f4v*)(op + (size_t)j * F4_));
    }
}

extern "C" void kernel_launch(void* const* d_in, const int* in_sizes, int n_in,
                              void* d_out, int out_size, void* d_ws, size_t ws_size,
                              hipStream_t stream) {
    const float4* x4 = (const float4*)d_in[0];
    float4*       o4 = (float4*)d_out;

    pcen_fused<<<dim3(NG_ * TB_), dim3(256), 0, stream>>>(x4, o4);
}

// Round 9
// 79.980 us; speedup vs baseline: 1.3150x; 1.1277x over previous
//
#include <hip/hip_runtime.h>
#include <math.h>

// PCEN, v5: persistent time-chains + prefetch across raw barrier.
//   block = 128 thr = 8 seq4 x 16 chunks(16 steps) = 256-step span;
//   each block walks a chain of 4 spans (1024 steps) sequentially.
//   carry = circular 16-chunk (256-step, validated) Horner over 32 LDS rows
//   (prev-span partials | cur-span partials), weight a^16 -> no serial state.
//   next-span loads issued BEFORE the barrier; raw s_barrier + lgkmcnt(0)
//   (not __syncthreads) so prefetch stays in flight -> per-wave steady-state
//   read/write mix instead of synchronized load/store phases.
//   halo (256 steps) read once per chain start -> read demand 1.25x.
//
// M[t] = a*M[t-1] + s*x[t], M[0]=x[0]
// out  = sqrt(x*(M+eps)^-0.98 + 2) - sqrt(2)

#define B_      64
#define T_      8192
#define F4_     20                // 80 f32 = 20 float4
#define NSEQ4   (B_ * F4_)        // 1280 float4 lanes
#define SPB_    8                 // seq4 per block
#define CPB_    16                // chunks per span
#define LCH_    16                // steps per chunk
#define SPAN_   (CPB_ * LCH_)     // 256
#define SPC_    4                 // spans per chain
#define CHAIN_  (SPC_ * SPAN_)    // 1024
#define TSPLIT_ (T_ / CHAIN_)     // 8 chains per seq
#define NG_     (NSEQ4 / SPB_)    // 160 seq groups -> grid 1280
#define SA_     0.025f
#define AA_     0.975f
#define A8_     0.81665182f       // 0.975^8
#define A16_    0.66692016f       // 0.975^16
#define A16S_   26.676807f        // A16_/SA_ (chunk-0 exact fix, u-space)

typedef float f4v __attribute__((ext_vector_type(4)));

__device__ __forceinline__ float pcen1(float xv, float m) {
    float l = __builtin_amdgcn_logf(m + 1e-6f);        // v_log_f32 (log2)
    float g = __builtin_amdgcn_exp2f(-0.98f * l);      // (m+eps)^(-alpha)
    return __builtin_amdgcn_sqrtf(fmaf(xv, g, 2.0f)) - 1.4142135623730951f;
}

__device__ __forceinline__ f4v pcen4(float4 xv, float4 m) {
    f4v o;
    o.x = pcen1(xv.x, m.x);
    o.y = pcen1(xv.y, m.y);
    o.z = pcen1(xv.z, m.z);
    o.w = pcen1(xv.w, m.w);
    return o;
}

// d = c*d + v
__device__ __forceinline__ void hstep(float4& d, float c, const float4 v) {
    d.x = fmaf(c, d.x, v.x);
    d.y = fmaf(c, d.y, v.y);
    d.z = fmaf(c, d.z, v.z);
    d.w = fmaf(c, d.w, v.w);
}

// d += c*v
__device__ __forceinline__ void faxpy(float4& d, float c, const float4 v) {
    d.x = fmaf(c, v.x, d.x);
    d.y = fmaf(c, v.y, d.y);
    d.z = fmaf(c, v.z, d.z);
    d.w = fmaf(c, v.w, d.w);
}

// m = a*m + s*x
__device__ __forceinline__ void ema4(float4& m, const float4 xv) {
    m.x = fmaf(AA_, m.x, SA_ * xv.x);
    m.y = fmaf(AA_, m.y, SA_ * xv.y);
    m.z = fmaf(AA_, m.z, SA_ * xv.z);
    m.w = fmaf(AA_, m.w, SA_ * xv.w);
}

// lgkmcnt-only barrier: LDS visibility without draining vmcnt (prefetch
// stays in flight across the barrier).
__device__ __forceinline__ void lds_barrier() {
    asm volatile("s_waitcnt lgkmcnt(0)" ::: "memory");
    __builtin_amdgcn_s_barrier();
}

// One span: partial -> LDS(cur half), prefetch next span, barrier,
// circular Horner carry, barrier, produce + NT stores.
// PB = prev-half base row (16 or 0); cur half = PB^16.
template <int PB, bool PREFETCH>
__device__ __forceinline__ void one_span(
    float4 (&cur)[LCH_], float4 (&nxt)[LCH_],
    const float4* __restrict__ xnext,
    const int s, const int lc,
    const float fixP, const float fixM,
    float4 (*P)[SPB_],
    float4* __restrict__ op)
{
    // ---- u-space partial of cur chunk (two 8-chains) ----
    float4 u0 = make_float4(0.f, 0.f, 0.f, 0.f);
    float4 u1 = make_float4(0.f, 0.f, 0.f, 0.f);
    #pragma unroll
    for (int j = 0; j < 8; ++j) {
        hstep(u0, AA_, cur[j]);
        hstep(u1, AA_, cur[j + 8]);
    }
    float4 pu = u1;
    faxpy(pu, A8_, u0);
    faxpy(pu, fixP, cur[0]);               // chunk-0 exact fix (usually 0)
    P[(PB ^ 16) + lc][s] = pu;

    // ---- prefetch next span (in flight across the barrier) ----
    if (PREFETCH) {
        #pragma unroll
        for (int j = 0; j < LCH_; ++j) nxt[j] = xnext[(size_t)j * F4_];
    }

    lds_barrier();

    // ---- carry: circular 16-term Horner, rows (PB+lc+k)&31, oldest->newest
    float4 u = P[(PB + lc) & 31][s];
    #pragma unroll
    for (int k = 1; k < CPB_; ++k) hstep(u, A16_, P[(PB + lc + k) & 31][s]);

    lds_barrier();                         // reads done before next overwrite

    float4 m;
    m.x = SA_ * u.x; m.y = SA_ * u.y; m.z = SA_ * u.z; m.w = SA_ * u.w;

    // ---- produce: EMA + pcen, NT stores ----
    ema4(m, cur[0]);
    faxpy(m, fixM, cur[0]);                // global t=0: m = x[0] exactly
    __builtin_nontemporal_store(pcen4(cur[0], m), (f4v*)op);
    #pragma unroll
    for (int j = 1; j < LCH_; ++j) {
        ema4(m, cur[j]);
        __builtin_nontemporal_store(pcen4(cur[j], m), (f4v*)(op + (size_t)j * F4_));
    }
}

__global__ void __launch_bounds__(128, 3)
pcen_chain(const float4* __restrict__ x4, float4* __restrict__ o4) {
    __shared__ float4 P[2 * CPB_][SPB_];   // 32 rows, circular halves

    const int tid = threadIdx.x;
    const int s   = tid & (SPB_ - 1);      // seq4 within block
    const int lc  = tid >> 3;              // chunk 0..15

    const int g     = blockIdx.x % NG_;
    const int chain = blockIdx.x / NG_;

    const int r  = g * SPB_ + s;
    const int b  = r / F4_;
    const int f4 = r - b * F4_;

    const float4* xbase = x4 + (size_t)b * ((size_t)T_ * F4_) + f4;
    float4*       obase = o4 + (size_t)b * ((size_t)T_ * F4_) + f4;

    const int t00 = chain * CHAIN_ + lc * LCH_;   // span-0 chunk start

    float4 xA[LCH_], xB[LCH_];

    // span-0 loads
    const float4* pc = xbase + (size_t)t00 * F4_;
    #pragma unroll
    for (int j = 0; j < LCH_; ++j) xA[j] = pc[(size_t)j * F4_];

    // halo partials -> prev half (rows 16..31); zeros for chain 0
    if (chain > 0) {                       // block-uniform branch
        const float4* ph = pc - (size_t)SPAN_ * F4_;
        #pragma unroll
        for (int j = 0; j < LCH_; ++j) xB[j] = ph[(size_t)j * F4_];
        float4 u0 = make_float4(0.f, 0.f, 0.f, 0.f);
        float4 u1 = make_float4(0.f, 0.f, 0.f, 0.f);
        #pragma unroll
        for (int j = 0; j < 8; ++j) {
            hstep(u0, AA_, xB[j]);
            hstep(u1, AA_, xB[j + 8]);
        }
        float4 hu = u1;
        faxpy(hu, A8_, u0);
        P[CPB_ + lc][s] = hu;
    } else {
        P[CPB_ + lc][s] = make_float4(0.f, 0.f, 0.f, 0.f);
    }

    const bool  c0   = (chain == 0 && lc == 0);
    const float fixP = c0 ? A16S_ : 0.0f;
    const float fixM = c0 ? AA_   : 0.0f;

    float4*       op = obase + (size_t)t00 * F4_;
    const size_t  so = (size_t)SPAN_ * F4_;

    one_span<16, true >(xA, xB, pc + so,     s, lc, fixP, fixM, P, op);
    one_span< 0, true >(xB, xA, pc + 2 * so, s, lc, 0.f,  0.f,  P, op + so);
    one_span<16, true >(xA, xB, pc + 3 * so, s, lc, 0.f,  0.f,  P, op + 2 * so);
    one_span< 0, false>(xB, xA, pc,          s, lc, 0.f,  0.f,  P, op + 3 * so);
}

extern "C" void kernel_launch(void* const* d_in, const int* in_sizes, int n_in,
                              void* d_out, int out_size, void* d_ws, size_t ws_size,
                              hipStream_t stream) {
    const float4* x4 = (const float4*)d_in[0];
    float4*       o4 = (float4*)d_out;

    pcen_chain<<<dim3(NG_ * TSPLIT_), dim3(128), 0, stream>>>(x4, o4);
}